// Round 9
// baseline (291.672 us; speedup 1.0000x reference)
//
#include <hip/hip_runtime.h>
#include <hip/hip_bf16.h>
#include <stdint.h>

#define T_TOK 2048
#define DIM 1024
#define FDIM 2048
#define NEXP 8
#define NSLOT 4096
#define MAXTILE 64

typedef short bf16x8 __attribute__((ext_vector_type(8)));
typedef unsigned short u16x8 __attribute__((ext_vector_type(8)));
typedef float f32x4 __attribute__((ext_vector_type(4)));

__device__ __forceinline__ unsigned short f2bf(float f) {
  union { float f; unsigned int u; } v; v.f = f;
  unsigned int r = v.u + 0x7FFFu + ((v.u >> 16) & 1u);
  return (unsigned short)(r >> 16);
}

__device__ __forceinline__ float bf2f(unsigned short x) {
  union { unsigned int u; float f; } v; v.u = ((unsigned int)x) << 16;
  return v.f;
}

__device__ __forceinline__ void gld_lds16(const void* g, void* l) {
  __builtin_amdgcn_global_load_lds(
      (const __attribute__((address_space(1))) unsigned int*)g,
      (__attribute__((address_space(3))) unsigned int*)l, 16, 0, 0);
}

#define PIPE_SYNC()                                        \
  __builtin_amdgcn_sched_barrier(0);                       \
  asm volatile("s_waitcnt vmcnt(0)" ::: "memory");         \
  __builtin_amdgcn_s_barrier();                            \
  __builtin_amdgcn_sched_barrier(0)

// ---------------- Router: fp32 exact, one wave per token ----------------
__global__ void router_kernel(const float* __restrict__ x, const float* __restrict__ rk,
                              int* __restrict__ counts, int* __restrict__ tok_e,
                              float* __restrict__ tok_w) {
  int w = threadIdx.x >> 6, lane = threadIdx.x & 63;
  int t = blockIdx.x * 4 + w;
  float acc[NEXP];
#pragma unroll
  for (int e = 0; e < NEXP; ++e) acc[e] = 0.f;
  const float4* xr = (const float4*)(x + (size_t)t * DIM);
#pragma unroll
  for (int i = 0; i < 4; ++i) {
    float4 xv = xr[i * 64 + lane];
    int d0 = (i * 64 + lane) * 4;
#pragma unroll
    for (int j = 0; j < 4; ++j) {
      const float4* rr = (const float4*)(rk + (size_t)(d0 + j) * NEXP);
      float4 r0 = rr[0], r1 = rr[1];
      float xs = (j == 0) ? xv.x : (j == 1) ? xv.y : (j == 2) ? xv.z : xv.w;
      acc[0] += xs * r0.x; acc[1] += xs * r0.y; acc[2] += xs * r0.z; acc[3] += xs * r0.w;
      acc[4] += xs * r1.x; acc[5] += xs * r1.y; acc[6] += xs * r1.z; acc[7] += xs * r1.w;
    }
  }
#pragma unroll
  for (int off = 32; off > 0; off >>= 1) {
#pragma unroll
    for (int e = 0; e < NEXP; ++e) acc[e] += __shfl_xor(acc[e], off, 64);
  }
  if (lane == 0) {
    float m = acc[0];
    for (int e = 1; e < NEXP; ++e) m = fmaxf(m, acc[e]);
    float p[NEXP], s = 0.f;
    for (int e = 0; e < NEXP; ++e) { p[e] = expf(acc[e] - m); s += p[e]; }
    float inv = 1.f / s;
    for (int e = 0; e < NEXP; ++e) p[e] *= inv;
    int i1 = 0;
    for (int e = 1; e < NEXP; ++e) if (p[e] > p[i1]) i1 = e;      // ties -> lowest idx
    int i2 = (i1 == 0) ? 1 : 0;
    for (int e = 0; e < NEXP; ++e) if (e != i1 && p[e] > p[i2]) i2 = e;
    // reference: softmax over the two top PROBABILITIES
    float e1 = expf(p[i1]), e2 = expf(p[i2]);
    float winv = 1.f / (e1 + e2);
    tok_e[t * 2] = i1; tok_e[t * 2 + 1] = i2;
    tok_w[t * 2] = e1 * winv; tok_w[t * 2 + 1] = e2 * winv;
    atomicAdd(&counts[i1], 1); atomicAdd(&counts[i2], 1);
  }
}

__global__ void scan_kernel(const int* __restrict__ counts, int* __restrict__ offsets,
                            int* __restrict__ tile_e, int* __restrict__ tile_mt,
                            int* __restrict__ ntiles) {
  if (threadIdx.x == 0) {
    int s = 0, t = 0;
    for (int e = 0; e < NEXP; ++e) {
      offsets[e] = s; s += counts[e];
      int nt = (counts[e] + 127) >> 7;
      for (int m = 0; m < nt; ++m) { tile_e[t] = e; tile_mt[t] = m; ++t; }
    }
    ntiles[0] = t;
  }
}

__global__ void assign_kernel(const int* __restrict__ tok_e, const float* __restrict__ tok_w,
                              const int* __restrict__ offsets, int* __restrict__ cursor,
                              int* __restrict__ slot_token, float* __restrict__ slot_weight,
                              int* __restrict__ tok_slot) {
  int t = blockIdx.x * 256 + threadIdx.x;
  if (t >= T_TOK) return;
#pragma unroll
  for (int k = 0; k < 2; ++k) {
    int e = tok_e[t * 2 + k];
    int pos = atomicAdd(&cursor[e], 1);
    int slot = offsets[e] + pos;
    slot_token[slot] = t;
    slot_weight[slot] = tok_w[t * 2 + k];
    tok_slot[t * 2 + k] = slot;
  }
}

// ---------------- Conversions ----------------
__global__ void cvt_x_kernel(const float* __restrict__ x, unsigned short* __restrict__ xb) {
  int i = blockIdx.x * 256 + threadIdx.x;  // T*D/8 threads
  const float4* p = (const float4*)x;
  float4 a = p[i * 2], b = p[i * 2 + 1];
  uint4 o;
  o.x = ((unsigned)f2bf(a.y) << 16) | f2bf(a.x);
  o.y = ((unsigned)f2bf(a.w) << 16) | f2bf(a.z);
  o.z = ((unsigned)f2bf(b.y) << 16) | f2bf(b.x);
  o.w = ((unsigned)f2bf(b.w) << 16) | f2bf(b.z);
  ((uint4*)xb)[i] = o;
}

// in fp32 [E][R][C] -> out bf16 [E][C][R]
__global__ void transpose_cvt_kernel(const float* __restrict__ in, unsigned short* __restrict__ out,
                                     int R, int C) {
  __shared__ float lds[64][65];
  int e = blockIdx.z;
  size_t base = (size_t)e * (size_t)R * (size_t)C;
  int rb = blockIdx.y * 64, cb = blockIdx.x * 64;
  int tid = threadIdx.x;
  int col4 = (tid & 15) * 4, row = tid >> 4;
#pragma unroll
  for (int it = 0; it < 4; ++it) {
    int r = row + it * 16;
    float4 v = *(const float4*)(in + base + (size_t)(rb + r) * C + cb + col4);
    lds[col4 + 0][r] = v.x; lds[col4 + 1][r] = v.y;
    lds[col4 + 2][r] = v.z; lds[col4 + 3][r] = v.w;
  }
  __syncthreads();
  int r2 = (tid & 31) * 2, c = tid >> 5;
#pragma unroll
  for (int it = 0; it < 8; ++it) {
    int cc = c + it * 8;
    unsigned v = ((unsigned)f2bf(lds[cc][r2 + 1]) << 16) | f2bf(lds[cc][r2]);
    *(unsigned*)(out + base + (size_t)(cb + cc) * R + rb + r2) = v;
  }
}

// GEMM (round 9): BK=32 double-buffered 2-phase (catalog T3-minimum recipe):
//   STAGE(next buf) -> compute(cur) -> [SB0] vmcnt(0) s_barrier [SB0]
// One barrier per step, issued-early stage hides its latency under the
// ds_read+MFMA phase. dbuf at BK=32 keeps LDS at 32KB/24KB so the r8
// 4-blocks/CU occupancy is preserved. sched_barrier(0) fences prevent MFMA
// sink past the barrier (rule #18) and stage hoist above it. Swizzle for
// 4-chunk rows: store chunk c^(r&3) via pre-swizzled source; read
// kof = ((lane>>4)^(lane&3))*8 -> 2 lanes/bank (free).

// ---------------- Pass A: fuse[slot][F] = silu(X@Wg) * (X@Wu) ----------------
__global__ __launch_bounds__(256) void gemm_gateup(
    const unsigned short* __restrict__ xb, const unsigned short* __restrict__ wg,
    const unsigned short* __restrict__ wu, const int* __restrict__ counts,
    const int* __restrict__ offsets, const int* __restrict__ slot_token,
    const int* __restrict__ tile_e, const int* __restrict__ tile_mt,
    const int* __restrict__ ntiles, unsigned short* __restrict__ fuse) {
  int ys = blockIdx.y;
  if (ys >= ntiles[0]) return;
  int e = tile_e[ys], mt = tile_mt[ys];
  int cnt = counts[e];
  int off = offsets[e];
  int nt = blockIdx.x;  // 32 tiles of 64 f-cols
  __shared__ unsigned short Al[2][128 * 32];
  __shared__ unsigned short Bgl[2][64 * 32];
  __shared__ unsigned short Bul[2][64 * 32];
  int tid = threadIdx.x, w = tid >> 6, lane = tid & 63;
  int csrc = (((lane & 3) ^ ((lane >> 2) & 3))) * 8;  // swizzled source chunk (elems)
  unsigned aoff[2];
  unsigned boff;
#pragma unroll
  for (int ii = 0; ii < 2; ++ii) {
    int j = ii * 4 + w;
    int r = j * 16 + (lane >> 2);
    int row = mt * 128 + r;
    int tok = (row < cnt) ? slot_token[off + row] : 0;  // clamp: garbage rows computed, not written
    aoff[ii] = (unsigned)(tok * DIM + csrc);
  }
  {
    int r = w * 16 + (lane >> 2);
    boff = (unsigned)((e * FDIM + nt * 64 + r) * DIM + csrc);
  }
  f32x4 accg[4][2] = {};
  f32x4 accu[4][2] = {};
  int wr = (w >> 1) * 64, wc = (w & 1) * 32;
  int kof = ((lane >> 4) ^ (lane & 3)) * 8;  // swizzled k-offset within 32-elem row

  auto stage = [&](int buf, int k0) {
    gld_lds16(xb + aoff[0] + k0, &Al[buf][(0 * 4 + w) * 512]);
    gld_lds16(xb + aoff[1] + k0, &Al[buf][(1 * 4 + w) * 512]);
    gld_lds16(wg + boff + k0, &Bgl[buf][w * 512]);
    gld_lds16(wu + boff + k0, &Bul[buf][w * 512]);
  };
  auto compute = [&](int buf) {
    bf16x8 af[4], bg[2], bu[2];
#pragma unroll
    for (int q = 0; q < 4; ++q)
      af[q] = *(const bf16x8*)&Al[buf][(wr + q * 16 + (lane & 15)) * 32 + kof];
#pragma unroll
    for (int q = 0; q < 2; ++q) {
      bg[q] = *(const bf16x8*)&Bgl[buf][(wc + q * 16 + (lane & 15)) * 32 + kof];
      bu[q] = *(const bf16x8*)&Bul[buf][(wc + q * 16 + (lane & 15)) * 32 + kof];
    }
#pragma unroll
    for (int m4 = 0; m4 < 4; ++m4) {
#pragma unroll
      for (int n4 = 0; n4 < 2; ++n4) {
        accg[m4][n4] = __builtin_amdgcn_mfma_f32_16x16x32_bf16(af[m4], bg[n4], accg[m4][n4], 0, 0, 0);
        accu[m4][n4] = __builtin_amdgcn_mfma_f32_16x16x32_bf16(af[m4], bu[n4], accu[m4][n4], 0, 0, 0);
      }
    }
  };

  // NT = DIM/32 = 32 K-tiles
  stage(0, 0);
  PIPE_SYNC();
  for (int t = 0; t < 30; t += 2) {
    stage(1, (t + 1) * 32);
    compute(0);
    PIPE_SYNC();
    stage(0, (t + 2) * 32);
    compute(1);
    PIPE_SYNC();
  }
  stage(1, 31 * 32);
  compute(0);
  PIPE_SYNC();
  compute(1);

#pragma unroll
  for (int m4 = 0; m4 < 4; ++m4) {
#pragma unroll
    for (int n4 = 0; n4 < 2; ++n4) {
      f32x4 g = accg[m4][n4], u = accu[m4][n4];
#pragma unroll
      for (int j = 0; j < 4; ++j) {
        int r = wr + m4 * 16 + (lane >> 4) * 4 + j;  // C layout: row=(lane>>4)*4+reg
        int row = mt * 128 + r;
        if (row < cnt) {
          float gv = g[j];
          float val = gv / (1.f + expf(-gv)) * u[j];
          int f = nt * 64 + wc + n4 * 16 + (lane & 15);  // col=lane&15
          fuse[(size_t)(off + row) * FDIM + f] = f2bf(val);
        }
      }
    }
  }
}

// ---------------- Pass B: part2[z][slot][D] = w_slot * (fuse[:,zK:(z+1)K] @ WdT) ----------------
__global__ __launch_bounds__(256) void gemm_down(
    const unsigned short* __restrict__ fuse, const unsigned short* __restrict__ wd,
    const int* __restrict__ counts, const int* __restrict__ offsets,
    const float* __restrict__ slot_weight, const int* __restrict__ tile_e,
    const int* __restrict__ tile_mt, const int* __restrict__ ntiles,
    unsigned short* __restrict__ part2) {
  int ys = blockIdx.y;
  if (ys >= ntiles[0]) return;
  int e = tile_e[ys], mt = tile_mt[ys];
  int cnt = counts[e];
  int off = offsets[e];
  int nt = blockIdx.x;   // 16 tiles of 64 d-cols
  int z = blockIdx.z;    // split-K half
  int kbase = z * (FDIM / 2);
  __shared__ unsigned short Al[2][128 * 32];
  __shared__ unsigned short Bl[2][64 * 32];
  int tid = threadIdx.x, w = tid >> 6, lane = tid & 63;
  int csrc = (((lane & 3) ^ ((lane >> 2) & 3))) * 8;
  unsigned aoff[2];
  unsigned boff;
#pragma unroll
  for (int ii = 0; ii < 2; ++ii) {
    int j = ii * 4 + w;
    int r = j * 16 + (lane >> 2);
    int row = mt * 128 + r;
    int grow = (row < cnt) ? (off + row) : off;  // clamp to valid memory
    aoff[ii] = (unsigned)(grow * FDIM + kbase + csrc);
  }
  {
    int r = w * 16 + (lane >> 2);
    boff = (unsigned)((e * DIM + nt * 64 + r) * FDIM + kbase + csrc);
  }
  f32x4 acc[4][2] = {};
  int wr = (w >> 1) * 64, wc = (w & 1) * 32;
  int kof = ((lane >> 4) ^ (lane & 3)) * 8;

  auto stage = [&](int buf, int k0) {
    gld_lds16(fuse + aoff[0] + k0, &Al[buf][(0 * 4 + w) * 512]);
    gld_lds16(fuse + aoff[1] + k0, &Al[buf][(1 * 4 + w) * 512]);
    gld_lds16(wd + boff + k0, &Bl[buf][w * 512]);
  };
  auto compute = [&](int buf) {
    bf16x8 af[4], bfr[2];
#pragma unroll
    for (int q = 0; q < 4; ++q)
      af[q] = *(const bf16x8*)&Al[buf][(wr + q * 16 + (lane & 15)) * 32 + kof];
#pragma unroll
    for (int q = 0; q < 2; ++q)
      bfr[q] = *(const bf16x8*)&Bl[buf][(wc + q * 16 + (lane & 15)) * 32 + kof];
#pragma unroll
    for (int m4 = 0; m4 < 4; ++m4) {
#pragma unroll
      for (int n4 = 0; n4 < 2; ++n4) {
        acc[m4][n4] = __builtin_amdgcn_mfma_f32_16x16x32_bf16(af[m4], bfr[n4], acc[m4][n4], 0, 0, 0);
      }
    }
  };

  // NT = (FDIM/2)/32 = 32 K-tiles
  stage(0, 0);
  PIPE_SYNC();
  for (int t = 0; t < 30; t += 2) {
    stage(1, (t + 1) * 32);
    compute(0);
    PIPE_SYNC();
    stage(0, (t + 2) * 32);
    compute(1);
    PIPE_SYNC();
  }
  stage(1, 31 * 32);
  compute(0);
  PIPE_SYNC();
  compute(1);

#pragma unroll
  for (int m4 = 0; m4 < 4; ++m4) {
#pragma unroll
    for (int j = 0; j < 4; ++j) {
      int r = wr + m4 * 16 + (lane >> 4) * 4 + j;
      int row = mt * 128 + r;
      if (row < cnt) {
        float wgt = slot_weight[off + row];
#pragma unroll
        for (int n4 = 0; n4 < 2; ++n4) {
          int d = nt * 64 + wc + n4 * 16 + (lane & 15);
          part2[((size_t)z * NSLOT + off + row) * DIM + d] = f2bf(acc[m4][n4][j] * wgt);
        }
      }
    }
  }
}

// ---------------- Combine: out[t] = sum over {slot0,slot1} x {split0,split1} ----------------
__global__ void combine_kernel(const unsigned short* __restrict__ part2,
                               const int* __restrict__ tok_slot, float* __restrict__ out) {
  int i = blockIdx.x * 256 + threadIdx.x;  // T*D/8 threads
  int t = i >> 7;
  int c = i & 127;  // 8-elem chunk within the D=1024 row
  int s0 = tok_slot[t * 2], s1 = tok_slot[t * 2 + 1];
  const u16x8* base = (const u16x8*)part2;
  u16x8 a0 = base[((size_t)s0) * (DIM / 8) + c];
  u16x8 a1 = base[((size_t)NSLOT + s0) * (DIM / 8) + c];
  u16x8 b0 = base[((size_t)s1) * (DIM / 8) + c];
  u16x8 b1 = base[((size_t)NSLOT + s1) * (DIM / 8) + c];
  float o[8];
#pragma unroll
  for (int j = 0; j < 8; ++j)
    o[j] = (bf2f(a0[j]) + bf2f(a1[j])) + (bf2f(b0[j]) + bf2f(b1[j]));
  float4* dst = (float4*)(out + (size_t)t * DIM + c * 8);
  dst[0] = make_float4(o[0], o[1], o[2], o[3]);
  dst[1] = make_float4(o[4], o[5], o[6], o[7]);
}

extern "C" void kernel_launch(void* const* d_in, const int* in_sizes, int n_in,
                              void* d_out, int out_size, void* d_ws, size_t ws_size,
                              hipStream_t stream) {
  (void)in_sizes; (void)n_in; (void)out_size;
  const float* x    = (const float*)d_in[0];
  const float* rk   = (const float*)d_in[1];
  const float* wg_f = (const float*)d_in[2];
  const float* wu_f = (const float*)d_in[3];
  const float* wd_f = (const float*)d_in[4];
  float* out = (float*)d_out;

  char* ws = (char*)d_ws;
  size_t o_xb   = 0;
  size_t o_wg   = o_xb + (size_t)T_TOK * DIM * 2;
  size_t o_wu   = o_wg + (size_t)NEXP * FDIM * DIM * 2;
  size_t o_wd   = o_wu + (size_t)NEXP * FDIM * DIM * 2;
  size_t o_fuse = o_wd + (size_t)NEXP * DIM * FDIM * 2;
  size_t o_part = o_fuse + (size_t)NSLOT * FDIM * 2;      // part2: 2 x NSLOT x DIM bf16
  size_t o_meta = o_part + (size_t)2 * NSLOT * DIM * 2;
  size_t o_counts = o_meta;
  size_t o_cursor = o_counts + 32;
  size_t o_offs   = o_cursor + 32;
  size_t o_tok_e  = o_offs + 32;
  size_t o_tok_w  = o_tok_e + (size_t)T_TOK * 2 * 4;
  size_t o_tok_s  = o_tok_w + (size_t)T_TOK * 2 * 4;
  size_t o_st     = o_tok_s + (size_t)T_TOK * 2 * 4;
  size_t o_sw     = o_st + (size_t)NSLOT * 4;
  size_t o_te     = o_sw + (size_t)NSLOT * 4;
  size_t o_tm     = o_te + MAXTILE * 4;
  size_t o_ntl    = o_tm + MAXTILE * 4;
  size_t need     = o_ntl + 32;
  if (ws_size < need) return;  // diagnostic: absmax will equal ~0.785 (zero output)

  unsigned short* xb    = (unsigned short*)(ws + o_xb);
  unsigned short* wgt   = (unsigned short*)(ws + o_wg);
  unsigned short* wut   = (unsigned short*)(ws + o_wu);
  unsigned short* wdt   = (unsigned short*)(ws + o_wd);
  unsigned short* fuse  = (unsigned short*)(ws + o_fuse);
  unsigned short* part2 = (unsigned short*)(ws + o_part);
  int* counts          = (int*)(ws + o_counts);
  int* cursor          = (int*)(ws + o_cursor);
  int* offsets         = (int*)(ws + o_offs);
  int* tok_e           = (int*)(ws + o_tok_e);
  float* tok_w         = (float*)(ws + o_tok_w);
  int* tok_slot        = (int*)(ws + o_tok_s);
  int* slot_token      = (int*)(ws + o_st);
  float* slot_weight   = (float*)(ws + o_sw);
  int* tile_e          = (int*)(ws + o_te);
  int* tile_mt         = (int*)(ws + o_tm);
  int* ntiles          = (int*)(ws + o_ntl);

  hipMemsetAsync(ws + o_counts, 0, 64, stream);  // counts + cursor
  router_kernel<<<T_TOK / 4, 256, 0, stream>>>(x, rk, counts, tok_e, tok_w);
  scan_kernel<<<1, 64, 0, stream>>>(counts, offsets, tile_e, tile_mt, ntiles);
  assign_kernel<<<T_TOK / 256, 256, 0, stream>>>(tok_e, tok_w, offsets, cursor,
                                                 slot_token, slot_weight, tok_slot);
  cvt_x_kernel<<<(T_TOK * DIM / 8) / 256, 256, 0, stream>>>(x, xb);
  transpose_cvt_kernel<<<dim3(FDIM / 64, DIM / 64, NEXP), 256, 0, stream>>>(wg_f, wgt, DIM, FDIM);
  transpose_cvt_kernel<<<dim3(FDIM / 64, DIM / 64, NEXP), 256, 0, stream>>>(wu_f, wut, DIM, FDIM);
  transpose_cvt_kernel<<<dim3(DIM / 64, FDIM / 64, NEXP), 256, 0, stream>>>(wd_f, wdt, FDIM, DIM);

  gemm_gateup<<<dim3(FDIM / 64, 40, 1), 256, 0, stream>>>(
      xb, wgt, wut, counts, offsets, slot_token, tile_e, tile_mt, ntiles, fuse);
  gemm_down<<<dim3(DIM / 64, 40, 2), 256, 0, stream>>>(
      fuse, wdt, counts, offsets, slot_weight, tile_e, tile_mt, ntiles, part2);
  combine_kernel<<<(T_TOK * DIM / 8) / 256, 256, 0, stream>>>(part2, tok_slot, out);
}

// Round 10
// 267.020 us; speedup vs baseline: 1.0923x; 1.0923x over previous
//
#include <hip/hip_runtime.h>
#include <hip/hip_bf16.h>
#include <stdint.h>

#define T_TOK 2048
#define DIM 1024
#define FDIM 2048
#define NEXP 8
#define NSLOT 4096
#define MAXTILE 64

typedef short bf16x8 __attribute__((ext_vector_type(8)));
typedef unsigned short u16x8 __attribute__((ext_vector_type(8)));
typedef float f32x4 __attribute__((ext_vector_type(4)));

__device__ __forceinline__ unsigned short f2bf(float f) {
  union { float f; unsigned int u; } v; v.f = f;
  unsigned int r = v.u + 0x7FFFu + ((v.u >> 16) & 1u);
  return (unsigned short)(r >> 16);
}

__device__ __forceinline__ float bf2f(unsigned short x) {
  union { unsigned int u; float f; } v; v.u = ((unsigned int)x) << 16;
  return v.f;
}

__device__ __forceinline__ void gld_lds16(const void* g, void* l) {
  __builtin_amdgcn_global_load_lds(
      (const __attribute__((address_space(1))) unsigned int*)g,
      (__attribute__((address_space(3))) unsigned int*)l, 16, 0, 0);
}

// ---------------- Router: fp32 exact, one wave per token ----------------
__global__ void router_kernel(const float* __restrict__ x, const float* __restrict__ rk,
                              int* __restrict__ counts, int* __restrict__ tok_e,
                              float* __restrict__ tok_w) {
  int w = threadIdx.x >> 6, lane = threadIdx.x & 63;
  int t = blockIdx.x * 4 + w;
  float acc[NEXP];
#pragma unroll
  for (int e = 0; e < NEXP; ++e) acc[e] = 0.f;
  const float4* xr = (const float4*)(x + (size_t)t * DIM);
#pragma unroll
  for (int i = 0; i < 4; ++i) {
    float4 xv = xr[i * 64 + lane];
    int d0 = (i * 64 + lane) * 4;
#pragma unroll
    for (int j = 0; j < 4; ++j) {
      const float4* rr = (const float4*)(rk + (size_t)(d0 + j) * NEXP);
      float4 r0 = rr[0], r1 = rr[1];
      float xs = (j == 0) ? xv.x : (j == 1) ? xv.y : (j == 2) ? xv.z : xv.w;
      acc[0] += xs * r0.x; acc[1] += xs * r0.y; acc[2] += xs * r0.z; acc[3] += xs * r0.w;
      acc[4] += xs * r1.x; acc[5] += xs * r1.y; acc[6] += xs * r1.z; acc[7] += xs * r1.w;
    }
  }
#pragma unroll
  for (int off = 32; off > 0; off >>= 1) {
#pragma unroll
    for (int e = 0; e < NEXP; ++e) acc[e] += __shfl_xor(acc[e], off, 64);
  }
  if (lane == 0) {
    float m = acc[0];
    for (int e = 1; e < NEXP; ++e) m = fmaxf(m, acc[e]);
    float p[NEXP], s = 0.f;
    for (int e = 0; e < NEXP; ++e) { p[e] = expf(acc[e] - m); s += p[e]; }
    float inv = 1.f / s;
    for (int e = 0; e < NEXP; ++e) p[e] *= inv;
    int i1 = 0;
    for (int e = 1; e < NEXP; ++e) if (p[e] > p[i1]) i1 = e;      // ties -> lowest idx
    int i2 = (i1 == 0) ? 1 : 0;
    for (int e = 0; e < NEXP; ++e) if (e != i1 && p[e] > p[i2]) i2 = e;
    // reference: softmax over the two top PROBABILITIES
    float e1 = expf(p[i1]), e2 = expf(p[i2]);
    float winv = 1.f / (e1 + e2);
    tok_e[t * 2] = i1; tok_e[t * 2 + 1] = i2;
    tok_w[t * 2] = e1 * winv; tok_w[t * 2 + 1] = e2 * winv;
    atomicAdd(&counts[i1], 1); atomicAdd(&counts[i2], 1);
  }
}

__global__ void scan_kernel(const int* __restrict__ counts, int* __restrict__ offsets,
                            int* __restrict__ tile_e, int* __restrict__ tile_mt,
                            int* __restrict__ ntiles) {
  if (threadIdx.x == 0) {
    int s = 0, t = 0;
    for (int e = 0; e < NEXP; ++e) {
      offsets[e] = s; s += counts[e];
      int nt = (counts[e] + 127) >> 7;
      for (int m = 0; m < nt; ++m) { tile_e[t] = e; tile_mt[t] = m; ++t; }
    }
    ntiles[0] = t;
  }
}

__global__ void assign_kernel(const int* __restrict__ tok_e, const float* __restrict__ tok_w,
                              const int* __restrict__ offsets, int* __restrict__ cursor,
                              int* __restrict__ slot_token, float* __restrict__ slot_weight,
                              int* __restrict__ tok_slot) {
  int t = blockIdx.x * 256 + threadIdx.x;
  if (t >= T_TOK) return;
#pragma unroll
  for (int k = 0; k < 2; ++k) {
    int e = tok_e[t * 2 + k];
    int pos = atomicAdd(&cursor[e], 1);
    int slot = offsets[e] + pos;
    slot_token[slot] = t;
    slot_weight[slot] = tok_w[t * 2 + k];
    tok_slot[t * 2 + k] = slot;
  }
}

// ---------------- Conversions ----------------
__global__ void cvt_x_kernel(const float* __restrict__ x, unsigned short* __restrict__ xb) {
  int i = blockIdx.x * 256 + threadIdx.x;  // T*D/8 threads
  const float4* p = (const float4*)x;
  float4 a = p[i * 2], b = p[i * 2 + 1];
  uint4 o;
  o.x = ((unsigned)f2bf(a.y) << 16) | f2bf(a.x);
  o.y = ((unsigned)f2bf(a.w) << 16) | f2bf(a.z);
  o.z = ((unsigned)f2bf(b.y) << 16) | f2bf(b.x);
  o.w = ((unsigned)f2bf(b.w) << 16) | f2bf(b.z);
  ((uint4*)xb)[i] = o;
}

// in fp32 [E][R][C] -> out bf16 [E][C][R]
__global__ void transpose_cvt_kernel(const float* __restrict__ in, unsigned short* __restrict__ out,
                                     int R, int C) {
  __shared__ float lds[64][65];
  int e = blockIdx.z;
  size_t base = (size_t)e * (size_t)R * (size_t)C;
  int rb = blockIdx.y * 64, cb = blockIdx.x * 64;
  int tid = threadIdx.x;
  int col4 = (tid & 15) * 4, row = tid >> 4;
#pragma unroll
  for (int it = 0; it < 4; ++it) {
    int r = row + it * 16;
    float4 v = *(const float4*)(in + base + (size_t)(rb + r) * C + cb + col4);
    lds[col4 + 0][r] = v.x; lds[col4 + 1][r] = v.y;
    lds[col4 + 2][r] = v.z; lds[col4 + 3][r] = v.w;
  }
  __syncthreads();
  int r2 = (tid & 31) * 2, c = tid >> 5;
#pragma unroll
  for (int it = 0; it < 8; ++it) {
    int cc = c + it * 8;
    unsigned v = ((unsigned)f2bf(lds[cc][r2 + 1]) << 16) | f2bf(lds[cc][r2]);
    *(unsigned*)(out + base + (size_t)(cb + cc) * R + rb + r2) = v;
  }
}

// GEMM (round 10): gateup reverted to exact r8 (best: 78us, conflicts 0,
// 4 blocks/CU). gemm_down upgraded to the same 43 FLOP/B fragment ratio:
// BN=128 (per-wave 64x64, acc 4x4) + split-K x4 to keep ~1056 real blocks
// = 4/CU. Partials (4 x NSLOT x DIM bf16 = 33.5MB) alias the dead wgt/wut
// region (weights are consumed by gateup before gemm_down launches; every
// call rewrites them in stream order -> deterministic).

// ---------------- Pass A: fuse[slot][F] = silu(X@Wg) * (X@Wu) ----------------
__global__ __launch_bounds__(256) void gemm_gateup(
    const unsigned short* __restrict__ xb, const unsigned short* __restrict__ wg,
    const unsigned short* __restrict__ wu, const int* __restrict__ counts,
    const int* __restrict__ offsets, const int* __restrict__ slot_token,
    const int* __restrict__ tile_e, const int* __restrict__ tile_mt,
    const int* __restrict__ ntiles, unsigned short* __restrict__ fuse) {
  int ys = blockIdx.y;
  if (ys >= ntiles[0]) return;
  int e = tile_e[ys], mt = tile_mt[ys];
  int cnt = counts[e];
  int off = offsets[e];
  int nt = blockIdx.x;  // 32 tiles of 64 f-cols
  __shared__ unsigned short Al[128 * 64];
  __shared__ unsigned short Bgl[64 * 64];
  __shared__ unsigned short Bul[64 * 64];
  int tid = threadIdx.x, w = tid >> 6, lane = tid & 63;
  int csrc = ((lane & 7) ^ (lane >> 3)) * 8;  // swizzled source chunk (bf16 elems)
  unsigned aoff[4];   // 32-bit element offsets (save VGPRs vs 64-bit ptrs)
  unsigned boff[2];   // same row offset for wg and wu
#pragma unroll
  for (int ii = 0; ii < 4; ++ii) {
    int r = (w * 4 + ii) * 8 + (lane >> 3);
    int row = mt * 128 + r;
    int tok = (row < cnt) ? slot_token[off + row] : 0;  // clamp: garbage rows computed, not written
    aoff[ii] = (unsigned)(tok * DIM + csrc);
  }
#pragma unroll
  for (int ii = 0; ii < 2; ++ii) {
    int r = (w * 2 + ii) * 8 + (lane >> 3);
    boff[ii] = (unsigned)((e * FDIM + nt * 64 + r) * DIM + csrc);
  }
  f32x4 accg[4][2] = {};
  f32x4 accu[4][2] = {};
  int wr = (w >> 1) * 64, wc = (w & 1) * 32;
  int swz = (lane & 7) << 3;
  int kof0 = ((lane >> 4) * 8) ^ swz;        // kk=0 swizzled col offset
  int kof1 = (32 + (lane >> 4) * 8) ^ swz;   // kk=1
  for (int k0 = 0; k0 < DIM; k0 += 64) {
#pragma unroll
    for (int ii = 0; ii < 4; ++ii)
      gld_lds16(xb + aoff[ii] + k0, &Al[(w * 4 + ii) * 512]);
#pragma unroll
    for (int ii = 0; ii < 2; ++ii) {
      gld_lds16(wg + boff[ii] + k0, &Bgl[(w * 2 + ii) * 512]);
      gld_lds16(wu + boff[ii] + k0, &Bul[(w * 2 + ii) * 512]);
    }
    __syncthreads();
#pragma unroll
    for (int kk = 0; kk < 2; ++kk) {
      int kof = kk ? kof1 : kof0;
      bf16x8 af[4], bg[2], bu[2];
#pragma unroll
      for (int q = 0; q < 4; ++q)
        af[q] = *(const bf16x8*)&Al[(wr + q * 16 + (lane & 15)) * 64 + kof];
#pragma unroll
      for (int q = 0; q < 2; ++q) {
        bg[q] = *(const bf16x8*)&Bgl[(wc + q * 16 + (lane & 15)) * 64 + kof];
        bu[q] = *(const bf16x8*)&Bul[(wc + q * 16 + (lane & 15)) * 64 + kof];
      }
#pragma unroll
      for (int m4 = 0; m4 < 4; ++m4) {
#pragma unroll
        for (int n4 = 0; n4 < 2; ++n4) {
          accg[m4][n4] = __builtin_amdgcn_mfma_f32_16x16x32_bf16(af[m4], bg[n4], accg[m4][n4], 0, 0, 0);
          accu[m4][n4] = __builtin_amdgcn_mfma_f32_16x16x32_bf16(af[m4], bu[n4], accu[m4][n4], 0, 0, 0);
        }
      }
    }
    __syncthreads();
  }
#pragma unroll
  for (int m4 = 0; m4 < 4; ++m4) {
#pragma unroll
    for (int n4 = 0; n4 < 2; ++n4) {
      f32x4 g = accg[m4][n4], u = accu[m4][n4];
#pragma unroll
      for (int j = 0; j < 4; ++j) {
        int r = wr + m4 * 16 + (lane >> 4) * 4 + j;  // C layout: row=(lane>>4)*4+reg
        int row = mt * 128 + r;
        if (row < cnt) {
          float gv = g[j];
          float val = gv / (1.f + expf(-gv)) * u[j];
          int f = nt * 64 + wc + n4 * 16 + (lane & 15);  // col=lane&15
          fuse[(size_t)(off + row) * FDIM + f] = f2bf(val);
        }
      }
    }
  }
}

// ---------------- Pass B: part4[z][slot][D] = w_slot * (fuse[:, z*512:(z+1)*512] @ WdT) ----------------
__global__ __launch_bounds__(256) void gemm_down(
    const unsigned short* __restrict__ fuse, const unsigned short* __restrict__ wd,
    const int* __restrict__ counts, const int* __restrict__ offsets,
    const float* __restrict__ slot_weight, const int* __restrict__ tile_e,
    const int* __restrict__ tile_mt, const int* __restrict__ ntiles,
    unsigned short* __restrict__ part4) {
  int ys = blockIdx.y;
  if (ys >= ntiles[0]) return;
  int e = tile_e[ys], mt = tile_mt[ys];
  int cnt = counts[e];
  int off = offsets[e];
  int nt = blockIdx.x;   // 8 tiles of 128 d-cols
  int z = blockIdx.z;    // split-K quarter
  int kbase = z * (FDIM / 4);
  __shared__ unsigned short Al[128 * 64];
  __shared__ unsigned short Bl[128 * 64];
  int tid = threadIdx.x, w = tid >> 6, lane = tid & 63;
  int csrc = ((lane & 7) ^ (lane >> 3)) * 8;
  unsigned aoff[4];
  unsigned boff[4];
#pragma unroll
  for (int ii = 0; ii < 4; ++ii) {
    int r = (w * 4 + ii) * 8 + (lane >> 3);
    int row = mt * 128 + r;
    int grow = (row < cnt) ? (off + row) : off;  // clamp to valid memory
    aoff[ii] = (unsigned)(grow * FDIM + kbase + csrc);
    boff[ii] = (unsigned)((e * DIM + nt * 128 + r) * FDIM + kbase + csrc);
  }
  f32x4 acc[4][4] = {};
  int wr = (w >> 1) * 64, wc = (w & 1) * 64;
  int swz = (lane & 7) << 3;
  int kof0 = ((lane >> 4) * 8) ^ swz;
  int kof1 = (32 + (lane >> 4) * 8) ^ swz;
  for (int k0 = 0; k0 < FDIM / 4; k0 += 64) {
#pragma unroll
    for (int ii = 0; ii < 4; ++ii) {
      gld_lds16(fuse + aoff[ii] + k0, &Al[(w * 4 + ii) * 512]);
      gld_lds16(wd + boff[ii] + k0, &Bl[(w * 4 + ii) * 512]);
    }
    __syncthreads();
#pragma unroll
    for (int kk = 0; kk < 2; ++kk) {
      int kof = kk ? kof1 : kof0;
      bf16x8 af[4], bfr[4];
#pragma unroll
      for (int q = 0; q < 4; ++q) {
        af[q] = *(const bf16x8*)&Al[(wr + q * 16 + (lane & 15)) * 64 + kof];
        bfr[q] = *(const bf16x8*)&Bl[(wc + q * 16 + (lane & 15)) * 64 + kof];
      }
#pragma unroll
      for (int m4 = 0; m4 < 4; ++m4) {
#pragma unroll
        for (int n4 = 0; n4 < 4; ++n4) {
          acc[m4][n4] = __builtin_amdgcn_mfma_f32_16x16x32_bf16(af[m4], bfr[n4], acc[m4][n4], 0, 0, 0);
        }
      }
    }
    __syncthreads();
  }
#pragma unroll
  for (int m4 = 0; m4 < 4; ++m4) {
#pragma unroll
    for (int j = 0; j < 4; ++j) {
      int r = wr + m4 * 16 + (lane >> 4) * 4 + j;
      int row = mt * 128 + r;
      if (row < cnt) {
        float wgt = slot_weight[off + row];
#pragma unroll
        for (int n4 = 0; n4 < 4; ++n4) {
          int d = nt * 128 + wc + n4 * 16 + (lane & 15);
          part4[((size_t)z * NSLOT + off + row) * DIM + d] = f2bf(acc[m4][n4][j] * wgt);
        }
      }
    }
  }
}

// ---------------- Combine: out[t] = sum over {slot0,slot1} x {z=0..3} ----------------
__global__ void combine_kernel(const unsigned short* __restrict__ part4,
                               const int* __restrict__ tok_slot, float* __restrict__ out) {
  int i = blockIdx.x * 256 + threadIdx.x;  // T*D/8 threads
  int t = i >> 7;
  int c = i & 127;  // 8-elem chunk within the D=1024 row
  int s0 = tok_slot[t * 2], s1 = tok_slot[t * 2 + 1];
  const u16x8* base = (const u16x8*)part4;
  float o[8];
#pragma unroll
  for (int j = 0; j < 8; ++j) o[j] = 0.f;
#pragma unroll
  for (int z = 0; z < 4; ++z) {
    u16x8 a = base[((size_t)z * NSLOT + s0) * (DIM / 8) + c];
    u16x8 b = base[((size_t)z * NSLOT + s1) * (DIM / 8) + c];
#pragma unroll
    for (int j = 0; j < 8; ++j) o[j] += bf2f(a[j]) + bf2f(b[j]);
  }
  float4* dst = (float4*)(out + (size_t)t * DIM + c * 8);
  dst[0] = make_float4(o[0], o[1], o[2], o[3]);
  dst[1] = make_float4(o[4], o[5], o[6], o[7]);
}

extern "C" void kernel_launch(void* const* d_in, const int* in_sizes, int n_in,
                              void* d_out, int out_size, void* d_ws, size_t ws_size,
                              hipStream_t stream) {
  (void)in_sizes; (void)n_in; (void)out_size;
  const float* x    = (const float*)d_in[0];
  const float* rk   = (const float*)d_in[1];
  const float* wg_f = (const float*)d_in[2];
  const float* wu_f = (const float*)d_in[3];
  const float* wd_f = (const float*)d_in[4];
  float* out = (float*)d_out;

  char* ws = (char*)d_ws;
  size_t o_xb   = 0;
  size_t o_wg   = o_xb + (size_t)T_TOK * DIM * 2;
  size_t o_wu   = o_wg + (size_t)NEXP * FDIM * DIM * 2;
  size_t o_wd   = o_wu + (size_t)NEXP * FDIM * DIM * 2;
  size_t o_fuse = o_wd + (size_t)NEXP * DIM * FDIM * 2;
  size_t o_part = o_fuse + (size_t)NSLOT * FDIM * 2;
  size_t o_meta = o_part + (size_t)2 * NSLOT * DIM * 2;
  size_t o_counts = o_meta;
  size_t o_cursor = o_counts + 32;
  size_t o_offs   = o_cursor + 32;
  size_t o_tok_e  = o_offs + 32;
  size_t o_tok_w  = o_tok_e + (size_t)T_TOK * 2 * 4;
  size_t o_tok_s  = o_tok_w + (size_t)T_TOK * 2 * 4;
  size_t o_st     = o_tok_s + (size_t)T_TOK * 2 * 4;
  size_t o_sw     = o_st + (size_t)NSLOT * 4;
  size_t o_te     = o_sw + (size_t)NSLOT * 4;
  size_t o_tm     = o_te + MAXTILE * 4;
  size_t o_ntl    = o_tm + MAXTILE * 4;
  size_t need     = o_ntl + 32;
  if (ws_size < need) return;  // diagnostic: absmax will equal ~0.785 (zero output)

  unsigned short* xb    = (unsigned short*)(ws + o_xb);
  unsigned short* wgt   = (unsigned short*)(ws + o_wg);
  unsigned short* wut   = (unsigned short*)(ws + o_wu);
  unsigned short* wdt   = (unsigned short*)(ws + o_wd);
  unsigned short* fuse  = (unsigned short*)(ws + o_fuse);
  // part4 (4 x NSLOT x DIM bf16 = 33.5MB) aliases wgt+wut (64MB): those are
  // dead once gemm_gateup has run; stream order makes the reuse deterministic.
  unsigned short* part4 = (unsigned short*)(ws + o_wg);
  int* counts          = (int*)(ws + o_counts);
  int* cursor          = (int*)(ws + o_cursor);
  int* offsets         = (int*)(ws + o_offs);
  int* tok_e           = (int*)(ws + o_tok_e);
  float* tok_w         = (float*)(ws + o_tok_w);
  int* tok_slot        = (int*)(ws + o_tok_s);
  int* slot_token      = (int*)(ws + o_st);
  float* slot_weight   = (float*)(ws + o_sw);
  int* tile_e          = (int*)(ws + o_te);
  int* tile_mt         = (int*)(ws + o_tm);
  int* ntiles          = (int*)(ws + o_ntl);

  hipMemsetAsync(ws + o_counts, 0, 64, stream);  // counts + cursor
  router_kernel<<<T_TOK / 4, 256, 0, stream>>>(x, rk, counts, tok_e, tok_w);
  scan_kernel<<<1, 64, 0, stream>>>(counts, offsets, tile_e, tile_mt, ntiles);
  assign_kernel<<<T_TOK / 256, 256, 0, stream>>>(tok_e, tok_w, offsets, cursor,
                                                 slot_token, slot_weight, tok_slot);
  cvt_x_kernel<<<(T_TOK * DIM / 8) / 256, 256, 0, stream>>>(x, xb);
  transpose_cvt_kernel<<<dim3(FDIM / 64, DIM / 64, NEXP), 256, 0, stream>>>(wg_f, wgt, DIM, FDIM);
  transpose_cvt_kernel<<<dim3(FDIM / 64, DIM / 64, NEXP), 256, 0, stream>>>(wu_f, wut, DIM, FDIM);
  transpose_cvt_kernel<<<dim3(DIM / 64, FDIM / 64, NEXP), 256, 0, stream>>>(wd_f, wdt, FDIM, DIM);

  gemm_gateup<<<dim3(FDIM / 64, 40, 1), 256, 0, stream>>>(
      xb, wgt, wut, counts, offsets, slot_token, tile_e, tile_mt, ntiles, fuse);
  gemm_down<<<dim3(DIM / 128, 40, 4), 256, 0, stream>>>(
      fuse, wdt, counts, offsets, slot_weight, tile_e, tile_mt, ntiles, part4);
  combine_kernel<<<(T_TOK * DIM / 8) / 256, 256, 0, stream>>>(part4, tok_slot, out);
}

// Round 11
// 249.297 us; speedup vs baseline: 1.1700x; 1.0711x over previous
//
#include <hip/hip_runtime.h>
#include <hip/hip_bf16.h>
#include <stdint.h>

#define T_TOK 2048
#define DIM 1024
#define FDIM 2048
#define NEXP 8
#define NSLOT 4096

typedef short bf16x8 __attribute__((ext_vector_type(8)));
typedef unsigned short u16x8 __attribute__((ext_vector_type(8)));
typedef float f32x4 __attribute__((ext_vector_type(4)));

__device__ __forceinline__ unsigned short f2bf(float f) {
  union { float f; unsigned int u; } v; v.f = f;
  unsigned int r = v.u + 0x7FFFu + ((v.u >> 16) & 1u);
  return (unsigned short)(r >> 16);
}

__device__ __forceinline__ float bf2f(unsigned short x) {
  union { unsigned int u; float f; } v; v.u = ((unsigned int)x) << 16;
  return v.f;
}

__device__ __forceinline__ void gld_lds16(const void* g, void* l) {
  __builtin_amdgcn_global_load_lds(
      (const __attribute__((address_space(1))) unsigned int*)g,
      (__attribute__((address_space(3))) unsigned int*)l, 16, 0, 0);
}

// ---------------- Router: fp32 exact, one wave per token; also emits xb (bf16 x) ----------------
__global__ void router_kernel(const float* __restrict__ x, const float* __restrict__ rk,
                              int* __restrict__ counts, int* __restrict__ tok_e,
                              float* __restrict__ tok_w, unsigned short* __restrict__ xb) {
  int w = threadIdx.x >> 6, lane = threadIdx.x & 63;
  int t = blockIdx.x * 4 + w;
  float acc[NEXP];
#pragma unroll
  for (int e = 0; e < NEXP; ++e) acc[e] = 0.f;
  const float4* xr = (const float4*)(x + (size_t)t * DIM);
#pragma unroll
  for (int i = 0; i < 4; ++i) {
    float4 xv = xr[i * 64 + lane];
    // fused x -> bf16 conversion (x already in registers)
    uint2 pk;
    pk.x = ((unsigned)f2bf(xv.y) << 16) | f2bf(xv.x);
    pk.y = ((unsigned)f2bf(xv.w) << 16) | f2bf(xv.z);
    *(uint2*)(xb + (size_t)t * DIM + (i * 64 + lane) * 4) = pk;
    int d0 = (i * 64 + lane) * 4;
#pragma unroll
    for (int j = 0; j < 4; ++j) {
      const float4* rr = (const float4*)(rk + (size_t)(d0 + j) * NEXP);
      float4 r0 = rr[0], r1 = rr[1];
      float xs = (j == 0) ? xv.x : (j == 1) ? xv.y : (j == 2) ? xv.z : xv.w;
      acc[0] += xs * r0.x; acc[1] += xs * r0.y; acc[2] += xs * r0.z; acc[3] += xs * r0.w;
      acc[4] += xs * r1.x; acc[5] += xs * r1.y; acc[6] += xs * r1.z; acc[7] += xs * r1.w;
    }
  }
#pragma unroll
  for (int off = 32; off > 0; off >>= 1) {
#pragma unroll
    for (int e = 0; e < NEXP; ++e) acc[e] += __shfl_xor(acc[e], off, 64);
  }
  if (lane == 0) {
    float m = acc[0];
    for (int e = 1; e < NEXP; ++e) m = fmaxf(m, acc[e]);
    float p[NEXP], s = 0.f;
    for (int e = 0; e < NEXP; ++e) { p[e] = expf(acc[e] - m); s += p[e]; }
    float inv = 1.f / s;
    for (int e = 0; e < NEXP; ++e) p[e] *= inv;
    int i1 = 0;
    for (int e = 1; e < NEXP; ++e) if (p[e] > p[i1]) i1 = e;      // ties -> lowest idx
    int i2 = (i1 == 0) ? 1 : 0;
    for (int e = 0; e < NEXP; ++e) if (e != i1 && p[e] > p[i2]) i2 = e;
    // reference: softmax over the two top PROBABILITIES
    float e1 = expf(p[i1]), e2 = expf(p[i2]);
    float winv = 1.f / (e1 + e2);
    tok_e[t * 2] = i1; tok_e[t * 2 + 1] = i2;
    tok_w[t * 2] = e1 * winv; tok_w[t * 2 + 1] = e2 * winv;
    atomicAdd(&counts[i1], 1); atomicAdd(&counts[i2], 1);
  }
}

// ---------------- Assign: offsets computed inline from counts (no scan kernel) ----------------
__global__ void assign_kernel(const int* __restrict__ tok_e, const float* __restrict__ tok_w,
                              const int* __restrict__ counts, int* __restrict__ cursor,
                              int* __restrict__ slot_token, float* __restrict__ slot_weight,
                              int* __restrict__ tok_slot) {
  int t = blockIdx.x * 256 + threadIdx.x;
  if (t >= T_TOK) return;
#pragma unroll
  for (int k = 0; k < 2; ++k) {
    int e = tok_e[t * 2 + k];
    int off = 0;
#pragma unroll
    for (int j = 0; j < NEXP; ++j) off += (j < e) ? counts[j] : 0;  // predicated, no array
    int pos = atomicAdd(&cursor[e], 1);
    int slot = off + pos;
    slot_token[slot] = t;
    slot_weight[slot] = tok_w[t * 2 + k];
    tok_slot[t * 2 + k] = slot;
  }
}

// ---------------- Merged transpose+cvt: fp32 [E][R][C] -> bf16 [E][C][R], all 3 tensors ----------------
// blockIdx.x in [0,1536): 0-511 wg (32x16 tiles), 512-1023 wu, 1024-1535 wd (16x32).
// blockIdx.y = expert. Writes as uint2 (4 bf16 / 8B per store).
__global__ void transpose_all(const float* __restrict__ wg_f, const float* __restrict__ wu_f,
                              const float* __restrict__ wd_f, unsigned short* __restrict__ wgt,
                              unsigned short* __restrict__ wut, unsigned short* __restrict__ wdt) {
  __shared__ float lds[64][65];
  int bid = blockIdx.x, e = blockIdx.y;
  const float* in;
  unsigned short* out;
  int R, C, rb, cb;
  if (bid < 1024) {
    in = (bid < 512) ? wg_f : wu_f;
    out = (bid < 512) ? wgt : wut;
    int id = bid & 511;
    R = DIM; C = FDIM;
    cb = (id & 31) * 64; rb = (id >> 5) * 64;
  } else {
    in = wd_f; out = wdt;
    int id = bid - 1024;
    R = FDIM; C = DIM;
    cb = (id & 15) * 64; rb = (id >> 4) * 64;
  }
  size_t base = (size_t)e * (size_t)R * (size_t)C;
  int tid = threadIdx.x;
  int col4 = (tid & 15) * 4, row = tid >> 4;
#pragma unroll
  for (int it = 0; it < 4; ++it) {
    int r = row + it * 16;
    float4 v = *(const float4*)(in + base + (size_t)(rb + r) * C + cb + col4);
    lds[col4 + 0][r] = v.x; lds[col4 + 1][r] = v.y;
    lds[col4 + 2][r] = v.z; lds[col4 + 3][r] = v.w;
  }
  __syncthreads();
  int r4 = (tid & 15) * 4, c = tid >> 4;
#pragma unroll
  for (int it = 0; it < 4; ++it) {
    int cc = c + it * 16;
    uint2 v;
    v.x = ((unsigned)f2bf(lds[cc][r4 + 1]) << 16) | f2bf(lds[cc][r4]);
    v.y = ((unsigned)f2bf(lds[cc][r4 + 3]) << 16) | f2bf(lds[cc][r4 + 2]);
    *(uint2*)(out + base + (size_t)(cb + cc) * R + rb + r4) = v;
  }
}

// Uniform tile decode from counts: ys -> (e, mt, off, cnt). SALU loop, 8 iters.
__device__ __forceinline__ bool tile_decode(const int* counts, int ys, int& e, int& mt,
                                            int& off, int& cnt) {
  mt = ys; off = 0;
  for (e = 0; e < NEXP; ++e) {
    cnt = counts[e];
    int ntl = (cnt + 127) >> 7;
    if (mt < ntl) return true;
    mt -= ntl; off += cnt;
  }
  return false;
}

// ---------------- Pass A: fuse[slot][F] = silu(X@Wg) * (X@Wu) ----------------
__global__ __launch_bounds__(256) void gemm_gateup(
    const unsigned short* __restrict__ xb, const unsigned short* __restrict__ wg,
    const unsigned short* __restrict__ wu, const int* __restrict__ counts,
    const int* __restrict__ slot_token, unsigned short* __restrict__ fuse) {
  int e, mt, off, cnt;
  if (!tile_decode(counts, blockIdx.y, e, mt, off, cnt)) return;
  int nt = blockIdx.x;  // 32 tiles of 64 f-cols
  __shared__ unsigned short Al[128 * 64];
  __shared__ unsigned short Bgl[64 * 64];
  __shared__ unsigned short Bul[64 * 64];
  int tid = threadIdx.x, w = tid >> 6, lane = tid & 63;
  int csrc = ((lane & 7) ^ (lane >> 3)) * 8;  // swizzled source chunk (bf16 elems)
  unsigned aoff[4];
  unsigned boff[2];
#pragma unroll
  for (int ii = 0; ii < 4; ++ii) {
    int r = (w * 4 + ii) * 8 + (lane >> 3);
    int row = mt * 128 + r;
    int tok = (row < cnt) ? slot_token[off + row] : 0;  // clamp: garbage rows computed, not written
    aoff[ii] = (unsigned)(tok * DIM + csrc);
  }
#pragma unroll
  for (int ii = 0; ii < 2; ++ii) {
    int r = (w * 2 + ii) * 8 + (lane >> 3);
    boff[ii] = (unsigned)((e * FDIM + nt * 64 + r) * DIM + csrc);
  }
  f32x4 accg[4][2] = {};
  f32x4 accu[4][2] = {};
  int wr = (w >> 1) * 64, wc = (w & 1) * 32;
  int swz = (lane & 7) << 3;
  int kof0 = ((lane >> 4) * 8) ^ swz;        // kk=0 swizzled col offset
  int kof1 = (32 + (lane >> 4) * 8) ^ swz;   // kk=1
  for (int k0 = 0; k0 < DIM; k0 += 64) {
#pragma unroll
    for (int ii = 0; ii < 4; ++ii)
      gld_lds16(xb + aoff[ii] + k0, &Al[(w * 4 + ii) * 512]);
#pragma unroll
    for (int ii = 0; ii < 2; ++ii) {
      gld_lds16(wg + boff[ii] + k0, &Bgl[(w * 2 + ii) * 512]);
      gld_lds16(wu + boff[ii] + k0, &Bul[(w * 2 + ii) * 512]);
    }
    __syncthreads();
#pragma unroll
    for (int kk = 0; kk < 2; ++kk) {
      int kof = kk ? kof1 : kof0;
      bf16x8 af[4], bg[2], bu[2];
#pragma unroll
      for (int q = 0; q < 4; ++q)
        af[q] = *(const bf16x8*)&Al[(wr + q * 16 + (lane & 15)) * 64 + kof];
#pragma unroll
      for (int q = 0; q < 2; ++q) {
        bg[q] = *(const bf16x8*)&Bgl[(wc + q * 16 + (lane & 15)) * 64 + kof];
        bu[q] = *(const bf16x8*)&Bul[(wc + q * 16 + (lane & 15)) * 64 + kof];
      }
#pragma unroll
      for (int m4 = 0; m4 < 4; ++m4) {
#pragma unroll
        for (int n4 = 0; n4 < 2; ++n4) {
          accg[m4][n4] = __builtin_amdgcn_mfma_f32_16x16x32_bf16(af[m4], bg[n4], accg[m4][n4], 0, 0, 0);
          accu[m4][n4] = __builtin_amdgcn_mfma_f32_16x16x32_bf16(af[m4], bu[n4], accu[m4][n4], 0, 0, 0);
        }
      }
    }
    __syncthreads();
  }
#pragma unroll
  for (int m4 = 0; m4 < 4; ++m4) {
#pragma unroll
    for (int n4 = 0; n4 < 2; ++n4) {
      f32x4 g = accg[m4][n4], u = accu[m4][n4];
#pragma unroll
      for (int j = 0; j < 4; ++j) {
        int r = wr + m4 * 16 + (lane >> 4) * 4 + j;  // C layout: row=(lane>>4)*4+reg
        int row = mt * 128 + r;
        if (row < cnt) {
          float gv = g[j];
          float val = gv / (1.f + expf(-gv)) * u[j];
          int f = nt * 64 + wc + n4 * 16 + (lane & 15);  // col=lane&15
          fuse[(size_t)(off + row) * FDIM + f] = f2bf(val);
        }
      }
    }
  }
}

// ---------------- Pass B: part4[z][slot][D] = w_slot * (fuse[:, z*512:(z+1)*512] @ WdT) ----------------
__global__ __launch_bounds__(256) void gemm_down(
    const unsigned short* __restrict__ fuse, const unsigned short* __restrict__ wd,
    const int* __restrict__ counts, const float* __restrict__ slot_weight,
    unsigned short* __restrict__ part4) {
  int e, mt, off, cnt;
  if (!tile_decode(counts, blockIdx.y, e, mt, off, cnt)) return;
  int nt = blockIdx.x;   // 8 tiles of 128 d-cols
  int z = blockIdx.z;    // split-K quarter
  int kbase = z * (FDIM / 4);
  __shared__ unsigned short Al[128 * 64];
  __shared__ unsigned short Bl[128 * 64];
  int tid = threadIdx.x, w = tid >> 6, lane = tid & 63;
  int csrc = ((lane & 7) ^ (lane >> 3)) * 8;
  unsigned aoff[4];
  unsigned boff[4];
#pragma unroll
  for (int ii = 0; ii < 4; ++ii) {
    int r = (w * 4 + ii) * 8 + (lane >> 3);
    int row = mt * 128 + r;
    int grow = (row < cnt) ? (off + row) : off;  // clamp to valid memory
    aoff[ii] = (unsigned)(grow * FDIM + kbase + csrc);
    boff[ii] = (unsigned)((e * DIM + nt * 128 + r) * FDIM + kbase + csrc);
  }
  f32x4 acc[4][4] = {};
  int wr = (w >> 1) * 64, wc = (w & 1) * 64;
  int swz = (lane & 7) << 3;
  int kof0 = ((lane >> 4) * 8) ^ swz;
  int kof1 = (32 + (lane >> 4) * 8) ^ swz;
  for (int k0 = 0; k0 < FDIM / 4; k0 += 64) {
#pragma unroll
    for (int ii = 0; ii < 4; ++ii) {
      gld_lds16(fuse + aoff[ii] + k0, &Al[(w * 4 + ii) * 512]);
      gld_lds16(wd + boff[ii] + k0, &Bl[(w * 4 + ii) * 512]);
    }
    __syncthreads();
#pragma unroll
    for (int kk = 0; kk < 2; ++kk) {
      int kof = kk ? kof1 : kof0;
      bf16x8 af[4], bfr[4];
#pragma unroll
      for (int q = 0; q < 4; ++q) {
        af[q] = *(const bf16x8*)&Al[(wr + q * 16 + (lane & 15)) * 64 + kof];
        bfr[q] = *(const bf16x8*)&Bl[(wc + q * 16 + (lane & 15)) * 64 + kof];
      }
#pragma unroll
      for (int m4 = 0; m4 < 4; ++m4) {
#pragma unroll
        for (int n4 = 0; n4 < 4; ++n4) {
          acc[m4][n4] = __builtin_amdgcn_mfma_f32_16x16x32_bf16(af[m4], bfr[n4], acc[m4][n4], 0, 0, 0);
        }
      }
    }
    __syncthreads();
  }
#pragma unroll
  for (int m4 = 0; m4 < 4; ++m4) {
#pragma unroll
    for (int j = 0; j < 4; ++j) {
      int r = wr + m4 * 16 + (lane >> 4) * 4 + j;
      int row = mt * 128 + r;
      if (row < cnt) {
        float wgt = slot_weight[off + row];
#pragma unroll
        for (int n4 = 0; n4 < 4; ++n4) {
          int d = nt * 128 + wc + n4 * 16 + (lane & 15);
          part4[((size_t)z * NSLOT + off + row) * DIM + d] = f2bf(acc[m4][n4][j] * wgt);
        }
      }
    }
  }
}

// ---------------- Combine: out[t] = sum over {slot0,slot1} x {z=0..3} ----------------
__global__ void combine_kernel(const unsigned short* __restrict__ part4,
                               const int* __restrict__ tok_slot, float* __restrict__ out) {
  int i = blockIdx.x * 256 + threadIdx.x;  // T*D/8 threads
  int t = i >> 7;
  int c = i & 127;  // 8-elem chunk within the D=1024 row
  int s0 = tok_slot[t * 2], s1 = tok_slot[t * 2 + 1];
  const u16x8* base = (const u16x8*)part4;
  float o[8];
#pragma unroll
  for (int j = 0; j < 8; ++j) o[j] = 0.f;
#pragma unroll
  for (int z = 0; z < 4; ++z) {
    u16x8 a = base[((size_t)z * NSLOT + s0) * (DIM / 8) + c];
    u16x8 b = base[((size_t)z * NSLOT + s1) * (DIM / 8) + c];
#pragma unroll
    for (int j = 0; j < 8; ++j) o[j] += bf2f(a[j]) + bf2f(b[j]);
  }
  float4* dst = (float4*)(out + (size_t)t * DIM + c * 8);
  dst[0] = make_float4(o[0], o[1], o[2], o[3]);
  dst[1] = make_float4(o[4], o[5], o[6], o[7]);
}

extern "C" void kernel_launch(void* const* d_in, const int* in_sizes, int n_in,
                              void* d_out, int out_size, void* d_ws, size_t ws_size,
                              hipStream_t stream) {
  (void)in_sizes; (void)n_in; (void)out_size;
  const float* x    = (const float*)d_in[0];
  const float* rk   = (const float*)d_in[1];
  const float* wg_f = (const float*)d_in[2];
  const float* wu_f = (const float*)d_in[3];
  const float* wd_f = (const float*)d_in[4];
  float* out = (float*)d_out;

  char* ws = (char*)d_ws;
  size_t o_xb   = 0;
  size_t o_wg   = o_xb + (size_t)T_TOK * DIM * 2;
  size_t o_wu   = o_wg + (size_t)NEXP * FDIM * DIM * 2;
  size_t o_wd   = o_wu + (size_t)NEXP * FDIM * DIM * 2;
  size_t o_fuse = o_wd + (size_t)NEXP * DIM * FDIM * 2;
  size_t o_meta = o_fuse + (size_t)NSLOT * FDIM * 2;
  size_t o_counts = o_meta;
  size_t o_cursor = o_counts + 32;
  size_t o_tok_e  = o_cursor + 32;
  size_t o_tok_w  = o_tok_e + (size_t)T_TOK * 2 * 4;
  size_t o_tok_s  = o_tok_w + (size_t)T_TOK * 2 * 4;
  size_t o_st     = o_tok_s + (size_t)T_TOK * 2 * 4;
  size_t o_sw     = o_st + (size_t)NSLOT * 4;
  size_t need     = o_sw + (size_t)NSLOT * 4;
  if (ws_size < need) return;  // diagnostic: absmax will equal ~0.785 (zero output)

  unsigned short* xb    = (unsigned short*)(ws + o_xb);
  unsigned short* wgt   = (unsigned short*)(ws + o_wg);
  unsigned short* wut   = (unsigned short*)(ws + o_wu);
  unsigned short* wdt   = (unsigned short*)(ws + o_wd);
  unsigned short* fuse  = (unsigned short*)(ws + o_fuse);
  // part4 (4 x NSLOT x DIM bf16 = 33.5MB) aliases wgt+wut (64MB): dead after
  // gemm_gateup; every call rewrites them in stream order -> deterministic.
  unsigned short* part4 = (unsigned short*)(ws + o_wg);
  int* counts          = (int*)(ws + o_counts);
  int* cursor          = (int*)(ws + o_cursor);
  int* tok_e           = (int*)(ws + o_tok_e);
  float* tok_w         = (float*)(ws + o_tok_w);
  int* tok_slot        = (int*)(ws + o_tok_s);
  int* slot_token      = (int*)(ws + o_st);
  float* slot_weight   = (float*)(ws + o_sw);

  hipMemsetAsync(ws + o_counts, 0, 64, stream);  // counts + cursor
  router_kernel<<<T_TOK / 4, 256, 0, stream>>>(x, rk, counts, tok_e, tok_w, xb);
  assign_kernel<<<T_TOK / 256, 256, 0, stream>>>(tok_e, tok_w, counts, cursor,
                                                 slot_token, slot_weight, tok_slot);
  transpose_all<<<dim3(1536, NEXP), 256, 0, stream>>>(wg_f, wu_f, wd_f, wgt, wut, wdt);
  gemm_gateup<<<dim3(FDIM / 64, 40, 1), 256, 0, stream>>>(xb, wgt, wut, counts,
                                                          slot_token, fuse);
  gemm_down<<<dim3(DIM / 128, 40, 4), 256, 0, stream>>>(fuse, wdt, counts,
                                                        slot_weight, part4);
  combine_kernel<<<(T_TOK * DIM / 8) / 256, 256, 0, stream>>>(part4, tok_slot, out);
}